// Round 8
// baseline (144.999 us; speedup 1.0000x reference)
//
#include <hip/hip_runtime.h>
#include <hip/hip_bf16.h>
#include <math.h>

// Problem: B=1, T=2048, E=1024, H=16, DH=64, NB=10, ML=2048
// Pipeline (all bf16 MFMA):
//   Xb = bf16(X); WbT = [Wq*0.125|Wk|Wv|Wr]^T bf16; WpT = Wp^T bf16
//   Y[2048][3328] = Xb @ Wb + bias   (Q|K|V|R)
//   Vt[h][d][t] = V^T per head; BndT[2176][32] zero-padded bf16 band table
//   AO = flash-attention: 32x32x16 MFMA, swapped operands (lane = q),
//        P fully in-register via bit-field j-permutation, E-bias via mfma32
//   out = AO @ Wp + bp (f32)

typedef __attribute__((ext_vector_type(8)))  short bf16x8;
typedef __attribute__((ext_vector_type(4)))  float f32x4;
typedef __attribute__((ext_vector_type(16))) float f32x16;
typedef __attribute__((ext_vector_type(2)))  unsigned u32x2;

#define MFMA16(a,b,c) __builtin_amdgcn_mfma_f32_16x16x32_bf16((a),(b),(c),0,0,0)
#define MFMA32(a,b,c) __builtin_amdgcn_mfma_f32_32x32x16_bf16((a),(b),(c),0,0,0)
#define GLB(p)  ((const __attribute__((address_space(1))) void*)(p))
#define LDSP(p) ((__attribute__((address_space(3))) void*)(p))
#define LDY2 3328

__device__ __forceinline__ unsigned short f2bf(float x){
  unsigned u = __float_as_uint(x);
  u = (u + 0x7FFFu + ((u >> 16) & 1u)) >> 16;
  return (unsigned short)u;
}
__device__ __forceinline__ unsigned short f2bf_rn(float x){
  __hip_bfloat16 b = __float2bfloat16(x);
  return *reinterpret_cast<unsigned short*>(&b);
}
__device__ __forceinline__ unsigned pack2(float a, float b){
  return ((unsigned)f2bf_rn(a)) | (((unsigned)f2bf_rn(b)) << 16);
}

// ---------------- prep kernels ----------------

__global__ __launch_bounds__(256) void convert_x(const float* __restrict__ X,
                                                 unsigned short* __restrict__ Xb){
  const int i = (blockIdx.x * 256 + threadIdx.x) * 8;
  f32x4 a = *(const f32x4*)(X + i);
  f32x4 b = *(const f32x4*)(X + i + 4);
  bf16x8 v;
  v[0]=(short)f2bf(a.x); v[1]=(short)f2bf(a.y); v[2]=(short)f2bf(a.z); v[3]=(short)f2bf(a.w);
  v[4]=(short)f2bf(b.x); v[5]=(short)f2bf(b.y); v[6]=(short)f2bf(b.z); v[7]=(short)f2bf(b.w);
  *(bf16x8*)(Xb + i) = v;
}

// WbT[c][k]; Q columns prescaled by 1/sqrt(d)=0.125
__global__ __launch_bounds__(256) void pack_wbt(const float* __restrict__ Wq,
    const float* __restrict__ Wk, const float* __restrict__ Wv,
    const float* __restrict__ Wr, unsigned short* __restrict__ WbT){
  __shared__ float tile[64][65];
  const int k0 = blockIdx.x * 64, c0 = blockIdx.y * 64;
  const int tid = threadIdx.x;
  {
    const int r = tid >> 2, cs = (tid & 3) << 4;
    #pragma unroll
    for (int q = 0; q < 4; ++q){
      const int c = c0 + cs + q * 4;
      f32x4 v;
      if (c < 1024){
        v = *(const f32x4*)(Wq + (size_t)(k0+r)*1024 + c);
        v.x *= 0.125f; v.y *= 0.125f; v.z *= 0.125f; v.w *= 0.125f;
      }
      else if (c < 2048) v = *(const f32x4*)(Wk + (size_t)(k0+r)*1024 + (c-1024));
      else if (c < 3072) v = *(const f32x4*)(Wv + (size_t)(k0+r)*1024 + (c-2048));
      else if (c < 3232) v = *(const f32x4*)(Wr + (size_t)(k0+r)*160  + (c-3072));
      else               v = (f32x4){0.f,0.f,0.f,0.f};
      tile[r][cs+q*4+0]=v.x; tile[r][cs+q*4+1]=v.y; tile[r][cs+q*4+2]=v.z; tile[r][cs+q*4+3]=v.w;
    }
  }
  __syncthreads();
  const int c = tid >> 2, ks = (tid & 3) << 4;
  bf16x8 o0, o1;
  #pragma unroll
  for (int x = 0; x < 8; ++x) o0[x] = (short)f2bf(tile[ks + x][c]);
  #pragma unroll
  for (int x = 0; x < 8; ++x) o1[x] = (short)f2bf(tile[ks + 8 + x][c]);
  *(bf16x8*)(WbT + (size_t)(c0 + c) * 1024 + k0 + ks)     = o0;
  *(bf16x8*)(WbT + (size_t)(c0 + c) * 1024 + k0 + ks + 8) = o1;
}

__global__ __launch_bounds__(256) void transpose_wp(const float* __restrict__ Wp,
                                                    unsigned short* __restrict__ WpT){
  __shared__ float tile[64][65];
  const int k0 = blockIdx.x * 64, c0 = blockIdx.y * 64;
  const int tid = threadIdx.x;
  {
    const int r = tid >> 2, cs = (tid & 3) << 4;
    #pragma unroll
    for (int q = 0; q < 4; ++q){
      f32x4 v = *(const f32x4*)(Wp + (size_t)(k0+r)*1024 + c0 + cs + q*4);
      tile[r][cs+q*4+0]=v.x; tile[r][cs+q*4+1]=v.y; tile[r][cs+q*4+2]=v.z; tile[r][cs+q*4+3]=v.w;
    }
  }
  __syncthreads();
  const int c = tid >> 2, ks = (tid & 3) << 4;
  bf16x8 o0, o1;
  #pragma unroll
  for (int x = 0; x < 8; ++x) o0[x] = (short)f2bf(tile[ks + x][c]);
  #pragma unroll
  for (int x = 0; x < 8; ++x) o1[x] = (short)f2bf(tile[ks + 8 + x][c]);
  *(bf16x8*)(WpT + (size_t)(c0 + c) * 1024 + k0 + ks)     = o0;
  *(bf16x8*)(WpT + (size_t)(c0 + c) * 1024 + k0 + ks + 8) = o1;
}

__global__ void build_bias(const float* __restrict__ bq, const float* __restrict__ br,
                           float* __restrict__ bias){
  const int c = blockIdx.x * 256 + threadIdx.x;
  if (c >= 3328) return;
  float v = 0.f;
  if (c < 1024) v = bq[c] * 0.125f;
  else if (c >= 3072 && c < 3232) v = br[c - 3072];
  bias[c] = v;
}

// Vt[h][d][t] <- Y[t][2048 + h*64 + d]
__global__ __launch_bounds__(256) void vt_transpose(const unsigned short* __restrict__ Y,
                                                    unsigned short* __restrict__ Vt){
  __shared__ unsigned short tile[64][72];
  const int h = blockIdx.y, t0 = blockIdx.x * 64;
  const int tid = threadIdx.x;
  {
    const int r = tid >> 2, cs = (tid & 3) << 4;
    const unsigned short* src = Y + (size_t)(t0 + r) * LDY2 + 2048 + h * 64 + cs;
    *(bf16x8*)&tile[r][cs]     = *(const bf16x8*)src;
    *(bf16x8*)&tile[r][cs + 8] = *(const bf16x8*)(src + 8);
  }
  __syncthreads();
  const int d = tid >> 2, ts = (tid & 3) << 4;
  bf16x8 o0, o1;
  #pragma unroll
  for (int x = 0; x < 8; ++x) o0[x] = (short)tile[ts + x][d];
  #pragma unroll
  for (int x = 0; x < 8; ++x) o1[x] = (short)tile[ts + 8 + x][d];
  *(bf16x8*)(Vt + (size_t)(h*64 + d) * 2048 + t0 + ts)     = o0;
  *(bf16x8*)(Vt + (size_t)(h*64 + d) * 2048 + t0 + ts + 8) = o1;
}

// BndT[t'][32]: t' = rel + 64, t' in [0,2176); cols n<10 = bnd[n][rel], else 0
__global__ __launch_bounds__(256) void build_bndt(const float* __restrict__ bnd,
                                                  unsigned short* __restrict__ BndT){
  const int t = blockIdx.x * 256 + threadIdx.x;
  if (t >= 2176) return;
  const int rel = t - 64;
  unsigned short* dst = BndT + (size_t)t * 32;
  bf16x8 v0 = {}, v1 = {}, z = {};
  if (rel >= 0 && rel < 2048){
    #pragma unroll
    for (int n = 0; n < 8; ++n) v0[n] = (short)f2bf(bnd[n * 2048 + rel]);
    v1[0] = (short)f2bf(bnd[8 * 2048 + rel]);
    v1[1] = (short)f2bf(bnd[9 * 2048 + rel]);
  }
  *(bf16x8*)dst        = v0;
  *(bf16x8*)(dst + 8)  = v1;
  *(bf16x8*)(dst + 16) = z;
  *(bf16x8*)(dst + 24) = z;
}

// ---------------- bf16 MFMA GEMM (m97 structure) ----------------

__global__ __launch_bounds__(256) void gemm_bf16(
    const unsigned short* __restrict__ A,
    const unsigned short* __restrict__ BT,
    const float* __restrict__ bias,
    void* __restrict__ C, int ldc, int out_f32)
{
  __shared__ unsigned short As[128 * 64];
  __shared__ unsigned short Bs[128 * 64];
  const int tid = threadIdx.x;
  const int w = tid >> 6, lane = tid & 63;
  const int lid = lane & 15, lgrp = lane >> 4;
  const int wm = w >> 1, wn = w & 1;
  const int row0 = blockIdx.y << 7, col0 = blockIdx.x << 7;
  const int sr = lane >> 3;
  const int sc = (lane & 7) ^ sr;

  f32x4 acc[4][4] = {};

  for (int k0 = 0; k0 < 1024; k0 += 64){
    #pragma unroll
    for (int it = 0; it < 4; ++it){
      const int r0w = (w << 5) + (it << 3);
      const int r = r0w + sr;
      __builtin_amdgcn_global_load_lds(GLB(A  + (size_t)(row0 + r) * 1024 + k0 + (sc << 3)),
                                       LDSP(&As[r0w << 6]), 16, 0, 0);
      __builtin_amdgcn_global_load_lds(GLB(BT + (size_t)(col0 + r) * 1024 + k0 + (sc << 3)),
                                       LDSP(&Bs[r0w << 6]), 16, 0, 0);
    }
    __syncthreads();

    bf16x8 af[4][2], bfr[4][2];
    #pragma unroll
    for (int m = 0; m < 4; ++m){
      const int ra = wm * 64 + m * 16 + lid;
      const int rb = wn * 64 + m * 16 + lid;
      #pragma unroll
      for (int kk = 0; kk < 2; ++kk){
        const int kc = kk * 4 + lgrp;
        af[m][kk]  = *(const bf16x8*)&As[(ra << 6) + ((kc ^ (lid & 7)) << 3)];
        bfr[m][kk] = *(const bf16x8*)&Bs[(rb << 6) + ((kc ^ (lid & 7)) << 3)];
      }
    }
    #pragma unroll
    for (int m = 0; m < 4; ++m)
      #pragma unroll
      for (int n = 0; n < 4; ++n){
        acc[m][n] = MFMA16(af[m][0], bfr[n][0], acc[m][n]);
        acc[m][n] = MFMA16(af[m][1], bfr[n][1], acc[m][n]);
      }
    __syncthreads();
  }

  #pragma unroll
  for (int m = 0; m < 4; ++m){
    #pragma unroll
    for (int n = 0; n < 4; ++n){
      const int col = col0 + wn * 64 + n * 16 + lid;
      const float bv = bias[col];
      #pragma unroll
      for (int i = 0; i < 4; ++i){
        const int row = row0 + wm * 64 + m * 16 + lgrp * 4 + i;
        const float v = acc[m][n][i] + bv;
        if (out_f32) ((float*)C)[(size_t)row * ldc + col] = v;
        else ((unsigned short*)C)[(size_t)row * ldc + col] = f2bf(v);
      }
    }
  }
}

// ---------------- fused flash attention (32x32 swapped-operand MFMA) --------
// Block = 2 waves x 32 q-rows = 64 q. Wave's lane holds q = qs + (lane&31).
// S^T = mfma32(K, Q): lane's 32 S values (2 j-blocks x 16 regs) all for its q.
// j(reg,hi) = jb*32 + (reg&3) + 8*(reg>>2) + 4*hi.  Softmax: in-lane + xor32.
// PV uses j-permutation pi(jc,hi,m)=jb*32+16*jc1+8*m2+low+4*hi on BOTH the
// P register packing and the V^T LDS reads -> P never touches LDS.
// E-bias: E = mfma32(BndT_rows, R) -> lane holds E[q][t'], written as f32x4
// to per-wave El[32][100], gathered per-logit as 1 ds_read_b32.

__global__ __launch_bounds__(128) void attn_mfma(
    const unsigned short* __restrict__ Y,
    const unsigned short* __restrict__ Vt,
    const unsigned short* __restrict__ BndT,
    unsigned short* __restrict__ AO)
{
  __shared__ unsigned short Ks[2][64 * 64];   // [j][d] chunk-swizzled
  __shared__ unsigned short Vs[2][64 * 64];   // [d][j] chunk-swizzled
  __shared__ float El[2][32 * 100];           // per-wave E window [q][c]

  const int id = blockIdx.x;
  const int g = id >> 4, h = id & 15;
  const int qb = (g < 16) ? (31 - g) : (g - 16);   // pair long+short
  const int q0 = qb << 6;
  const int tid = threadIdx.x;
  const int w = tid >> 6, lane = tid & 63;
  const int l31 = lane & 31, hi = lane >> 5;
  const int sr = lane >> 3;
  const int scc = (lane & 7) ^ sr;

  const int qg = q0 + w * 32 + l31;           // this lane's global q row

  // Q fragments (loop-invariant): Q[qg][kc*16 + hi*8 + 0..7]
  bf16x8 qf[4];
  #pragma unroll
  for (int kc = 0; kc < 4; ++kc)
    qf[kc] = *(const bf16x8*)(Y + (size_t)qg * LDY2 + h * 64 + kc * 16 + hi * 8);

  // R fragment: R[qg][hi*8 + 0..7] (n<10 real, rest zero)
  bf16x8 rf = {};
  {
    const unsigned* rp = (const unsigned*)(Y + (size_t)qg * LDY2 + 3072 + h * 10);
    if (hi == 0){
      ((unsigned*)&rf)[0] = rp[0]; ((unsigned*)&rf)[1] = rp[1];
      ((unsigned*)&rf)[2] = rp[2]; ((unsigned*)&rf)[3] = rp[3];
    } else {
      ((unsigned*)&rf)[0] = rp[4];
    }
  }

  float m_i = -INFINITY, l_i = 0.f;
  f32x16 oA = {}, oB = {};
  float* elw = &El[w][0];

  // prologue: stage tile 0 (wave w stages rows w*32..+31 of K and V)
  #pragma unroll
  for (int it = 0; it < 4; ++it){
    const int r0w = w * 32 + it * 8;
    const int r = r0w + sr;
    __builtin_amdgcn_global_load_lds(GLB(Y  + (size_t)r * LDY2 + 1024 + h*64 + (scc << 3)),
                                     LDSP(&Ks[0][r0w << 6]), 16, 0, 0);
    __builtin_amdgcn_global_load_lds(GLB(Vt + (size_t)(h*64 + r) * 2048 + (scc << 3)),
                                     LDSP(&Vs[0][r0w << 6]), 16, 0, 0);
  }
  __syncthreads();

  int cur = 0;
  for (int kb = 0; kb <= qb; ++kb){
    const int j0 = kb << 6, d0 = q0 - j0;

    // prefetch next tile into the other buffer
    if (kb < qb){
      const int jn = j0 + 64;
      #pragma unroll
      for (int it = 0; it < 4; ++it){
        const int r0w = w * 32 + it * 8;
        const int r = r0w + sr;
        __builtin_amdgcn_global_load_lds(GLB(Y  + (size_t)(jn + r) * LDY2 + 1024 + h*64 + (scc << 3)),
                                         LDSP(&Ks[cur ^ 1][r0w << 6]), 16, 0, 0);
        __builtin_amdgcn_global_load_lds(GLB(Vt + (size_t)(h*64 + r) * 2048 + jn + (scc << 3)),
                                         LDSP(&Vs[cur ^ 1][r0w << 6]), 16, 0, 0);
      }
    }

    // E A-fragments: BndT rows t' = d0 + w*32 + 1 + e*32 + l31, k = hi*8..
    bf16x8 bwf[3];
    #pragma unroll
    for (int e = 0; e < 3; ++e){
      const int rowt = d0 + w * 32 + 1 + e * 32 + l31;
      bwf[e] = *(const bf16x8*)(BndT + ((size_t)rowt << 5) + hi * 8);
    }

    // S^T = K Q^T (2 j-blocks x 4 d-chunks)
    f32x16 s0 = {}, s1 = {};
    const unsigned short* ks = &Ks[cur][0];
    __builtin_amdgcn_s_setprio(1);
    #pragma unroll
    for (int kc = 0; kc < 4; ++kc){
      const int c8 = kc * 2 + hi;
      const int jr0 = l31, jr1 = 32 + l31;
      const bf16x8 kf0 = *(const bf16x8*)&ks[(jr0 << 6) + ((c8 ^ (jr0 & 7)) << 3)];
      const bf16x8 kf1 = *(const bf16x8*)&ks[(jr1 << 6) + ((c8 ^ (jr1 & 7)) << 3)];
      s0 = MFMA32(kf0, qf[kc], s0);
      s1 = MFMA32(kf1, qf[kc], s1);
    }
    __builtin_amdgcn_s_setprio(0);

    // E window: 3 MFMAs, conflict-free f32x4 stores (stride 100)
    #pragma unroll
    for (int e = 0; e < 3; ++e){
      f32x16 ef = {};
      ef = MFMA32(bwf[e], rf, ef);
      #pragma unroll
      for (int R2 = 0; R2 < 4; ++R2){
        f32x4 qv = { ef[R2*4+0], ef[R2*4+1], ef[R2*4+2], ef[R2*4+3] };
        *(f32x4*)&elw[l31 * 100 + e * 32 + R2 * 8 + hi * 4] = qv;
      }
    }

    // bias gather + causal mask: c = l31 + 63 - jl
    const bool diag = (kb == qb);
    const int ql = w * 32 + l31;
    const float* erow = &elw[l31 * 100 + l31 + 63 - hi * 4];
    #pragma unroll
    for (int r = 0; r < 16; ++r){
      const int joff = (r & 3) + 8 * (r >> 2);
      {
        const int jl = joff + 4 * hi;
        float v = s0[r] + erow[-joff];
        if (diag && jl > ql) v = -1e9f;
        s0[r] = v;
      }
      {
        const int jl = 32 + joff + 4 * hi;
        float v = s1[r] + erow[-32 - joff];
        if (diag && jl > ql) v = -1e9f;
        s1[r] = v;
      }
    }

    // online softmax (32 in-lane values + partner half via xor32)
    float rm = s0[0];
    #pragma unroll
    for (int r = 0; r < 16; ++r){ rm = fmaxf(rm, s0[r]); rm = fmaxf(rm, s1[r]); }
    rm = fmaxf(rm, __shfl_xor(rm, 32));
    const float mn = fmaxf(m_i, rm);
    const float sc_ = __expf(m_i - mn);
    m_i = mn;
    float rs = 0.f;
    #pragma unroll
    for (int r = 0; r < 16; ++r){
      const float p0 = __expf(s0[r] - mn); s0[r] = p0; rs += p0;
      const float p1 = __expf(s1[r] - mn); s1[r] = p1; rs += p1;
    }
    rs += __shfl_xor(rs, 32);
    l_i = l_i * sc_ + rs;
    #pragma unroll
    for (int r = 0; r < 16; ++r){ oA[r] *= sc_; oB[r] *= sc_; }

    // pack P in-register: pk[jb][R2] covers j = jb*32 + 8*R2 + 4*hi + 0..3
    unsigned pk0[4][2], pk1[4][2];
    #pragma unroll
    for (int R2 = 0; R2 < 4; ++R2){
      pk0[R2][0] = pack2(s0[R2*4+0], s0[R2*4+1]);
      pk0[R2][1] = pack2(s0[R2*4+2], s0[R2*4+3]);
      pk1[R2][0] = pack2(s1[R2*4+0], s1[R2*4+1]);
      pk1[R2][1] = pack2(s1[R2*4+2], s1[R2*4+3]);
    }

    // O^T += V^T P^T over permuted j: pi = jb*32 + 16*jc1 + 8*m2 + low + 4*hi
    const unsigned short* vs = &Vs[cur][0];
    __builtin_amdgcn_s_setprio(1);
    #pragma unroll
    for (int jc = 0; jc < 4; ++jc){
      const int jb = jc >> 1, jc1 = jc & 1;
      bf16x8 pb;
      ((unsigned*)&pb)[0] = jb ? pk1[2*jc1][0]     : pk0[2*jc1][0];
      ((unsigned*)&pb)[1] = jb ? pk1[2*jc1][1]     : pk0[2*jc1][1];
      ((unsigned*)&pb)[2] = jb ? pk1[2*jc1 + 1][0] : pk0[2*jc1 + 1][0];
      ((unsigned*)&pb)[3] = jb ? pk1[2*jc1 + 1][1] : pk0[2*jc1 + 1][1];
      const int ch0 = jb * 4 + jc1 * 2;
      #pragma unroll
      for (int db = 0; db < 2; ++db){
        const int d = db * 32 + l31;
        bf16x8 vf;
        *(u32x2*)&((unsigned*)&vf)[0] =
            *(const u32x2*)&vs[(d << 6) + ((ch0 ^ (d & 7)) << 3) + hi * 4];
        *(u32x2*)&((unsigned*)&vf)[2] =
            *(const u32x2*)&vs[(d << 6) + (((ch0 + 1) ^ (d & 7)) << 3) + hi * 4];
        if (db == 0) oA = MFMA32(vf, pb, oA);
        else         oB = MFMA32(vf, pb, oB);
      }
    }
    __builtin_amdgcn_s_setprio(0);

    __syncthreads();   // next tile fully staged; swap buffers
    cur ^= 1;
  }

  // epilogue: lane's q-row, d' = db*32 + 8*R2 + 4*hi + 0..3, 8B packed stores
  const float inv = 1.f / l_i;
  unsigned short* dst = AO + (size_t)qg * 1024 + h * 64;
  #pragma unroll
  for (int db = 0; db < 2; ++db){
    #pragma unroll
    for (int R2 = 0; R2 < 4; ++R2){
      const float v0 = (db ? oB[R2*4+0] : oA[R2*4+0]) * inv;
      const float v1 = (db ? oB[R2*4+1] : oA[R2*4+1]) * inv;
      const float v2 = (db ? oB[R2*4+2] : oA[R2*4+2]) * inv;
      const float v3 = (db ? oB[R2*4+3] : oA[R2*4+3]) * inv;
      const unsigned u0 = pack2(v0, v1);
      const unsigned u1 = pack2(v2, v3);
      unsigned long long pkd = ((unsigned long long)u1 << 32) | u0;
      *(unsigned long long*)(dst + db * 32 + R2 * 8 + hi * 4) = pkd;
    }
  }
}

// ---------------- launch ----------------

extern "C" void kernel_launch(void* const* d_in, const int* in_sizes, int n_in,
                              void* d_out, int out_size, void* d_ws, size_t ws_size,
                              hipStream_t stream) {
  const float* X   = (const float*)d_in[0];
  const float* Wq  = (const float*)d_in[1];
  const float* bq  = (const float*)d_in[2];
  const float* Wk  = (const float*)d_in[3];
  const float* Wv  = (const float*)d_in[4];
  const float* Wp  = (const float*)d_in[5];
  const float* bp  = (const float*)d_in[6];
  const float* Wr  = (const float*)d_in[7];
  const float* br  = (const float*)d_in[8];
  const float* bnd = (const float*)d_in[9];
  float* out = (float*)d_out;

  unsigned short* Xb  = (unsigned short*)d_ws;            // 2048*1024 (reused as AO)
  unsigned short* WbT = Xb  + (size_t)2048 * 1024;        // 3328*1024 (BndT alias after gemm)
  unsigned short* Yb  = WbT + (size_t)3328 * 1024;        // 2048*3328
  unsigned short* Vt  = Yb  + (size_t)2048 * 3328;        // 1024*2048
  unsigned short* WpT = Vt  + (size_t)1024 * 2048;        // 1024*1024
  float* bias = (float*)(WpT + (size_t)1024 * 1024);      // 3328
  unsigned short* AO   = Xb;    // Xb dead after projection GEMM
  unsigned short* BndT = WbT;   // WbT dead after projection GEMM

  convert_x   <<<1024,         256, 0, stream>>>(X, Xb);
  pack_wbt    <<<dim3(16, 52), 256, 0, stream>>>(Wq, Wk, Wv, Wr, WbT);
  transpose_wp<<<dim3(16, 16), 256, 0, stream>>>(Wp, WpT);
  build_bias  <<<13,           256, 0, stream>>>(bq, br, bias);

  gemm_bf16   <<<dim3(26, 16), 256, 0, stream>>>(Xb, WbT, bias, Yb, 3328, 0);
  vt_transpose<<<dim3(32, 16), 256, 0, stream>>>(Yb, Vt);
  build_bndt  <<<9,            256, 0, stream>>>(bnd, BndT);
  attn_mfma   <<<512,          128, 0, stream>>>(Yb, Vt, BndT, AO);
  gemm_bf16   <<<dim3(8, 16),  256, 0, stream>>>(AO, WpT, bp, out, 1024, 1);
}

// Round 9
// 127.346 us; speedup vs baseline: 1.1386x; 1.1386x over previous
//
#include <hip/hip_runtime.h>
#include <hip/hip_bf16.h>
#include <math.h>

// Problem: B=1, T=2048, E=1024, H=16, DH=64, NB=10, ML=2048
// Pipeline (all bf16 MFMA):
//   Xb = bf16(X); WbT = [Wq*0.125|Wk|Wv|Wr]^T bf16; WpT = Wp^T bf16
//   Y[2048][3328] = Xb @ Wb + bias   (Q|K|V|R)
//   Vt[h][d][t] = V^T per head; BndT[2176][32] zero-padded bf16 band table
//   AO = flash-attention: uniform-duration blocks (qb pair), 2 kv-parity
//        groups per block with in-LDS merge, r7 16x16 swapped-operand pipeline
//   out = AO @ Wp + bp (f32)

typedef __attribute__((ext_vector_type(8))) short bf16x8;
typedef __attribute__((ext_vector_type(4))) float f32x4;

#define MFMA16(a,b,c) __builtin_amdgcn_mfma_f32_16x16x32_bf16((a),(b),(c),0,0,0)
#define GLB(p)  ((const __attribute__((address_space(1))) void*)(p))
#define LDSP(p) ((__attribute__((address_space(3))) void*)(p))
#define LDY2 3328

__device__ __forceinline__ unsigned short f2bf(float x){
  unsigned u = __float_as_uint(x);
  u = (u + 0x7FFFu + ((u >> 16) & 1u)) >> 16;
  return (unsigned short)u;
}
__device__ __forceinline__ unsigned short f2bf_rn(float x){
  __hip_bfloat16 b = __float2bfloat16(x);
  return *reinterpret_cast<unsigned short*>(&b);
}
__device__ __forceinline__ float bf2f(unsigned short b){
  return __uint_as_float(((unsigned)b) << 16);
}

// ---------------- prep kernels ----------------

__global__ __launch_bounds__(256) void convert_x(const float* __restrict__ X,
                                                 unsigned short* __restrict__ Xb){
  const int i = (blockIdx.x * 256 + threadIdx.x) * 8;
  f32x4 a = *(const f32x4*)(X + i);
  f32x4 b = *(const f32x4*)(X + i + 4);
  bf16x8 v;
  v[0]=(short)f2bf(a.x); v[1]=(short)f2bf(a.y); v[2]=(short)f2bf(a.z); v[3]=(short)f2bf(a.w);
  v[4]=(short)f2bf(b.x); v[5]=(short)f2bf(b.y); v[6]=(short)f2bf(b.z); v[7]=(short)f2bf(b.w);
  *(bf16x8*)(Xb + i) = v;
}

// WbT[c][k]; Q columns prescaled by 1/sqrt(d)=0.125
__global__ __launch_bounds__(256) void pack_wbt(const float* __restrict__ Wq,
    const float* __restrict__ Wk, const float* __restrict__ Wv,
    const float* __restrict__ Wr, unsigned short* __restrict__ WbT){
  __shared__ float tile[64][65];
  const int k0 = blockIdx.x * 64, c0 = blockIdx.y * 64;
  const int tid = threadIdx.x;
  {
    const int r = tid >> 2, cs = (tid & 3) << 4;
    #pragma unroll
    for (int q = 0; q < 4; ++q){
      const int c = c0 + cs + q * 4;
      f32x4 v;
      if (c < 1024){
        v = *(const f32x4*)(Wq + (size_t)(k0+r)*1024 + c);
        v.x *= 0.125f; v.y *= 0.125f; v.z *= 0.125f; v.w *= 0.125f;
      }
      else if (c < 2048) v = *(const f32x4*)(Wk + (size_t)(k0+r)*1024 + (c-1024));
      else if (c < 3072) v = *(const f32x4*)(Wv + (size_t)(k0+r)*1024 + (c-2048));
      else if (c < 3232) v = *(const f32x4*)(Wr + (size_t)(k0+r)*160  + (c-3072));
      else               v = (f32x4){0.f,0.f,0.f,0.f};
      tile[r][cs+q*4+0]=v.x; tile[r][cs+q*4+1]=v.y; tile[r][cs+q*4+2]=v.z; tile[r][cs+q*4+3]=v.w;
    }
  }
  __syncthreads();
  const int c = tid >> 2, ks = (tid & 3) << 4;
  bf16x8 o0, o1;
  #pragma unroll
  for (int x = 0; x < 8; ++x) o0[x] = (short)f2bf(tile[ks + x][c]);
  #pragma unroll
  for (int x = 0; x < 8; ++x) o1[x] = (short)f2bf(tile[ks + 8 + x][c]);
  *(bf16x8*)(WbT + (size_t)(c0 + c) * 1024 + k0 + ks)     = o0;
  *(bf16x8*)(WbT + (size_t)(c0 + c) * 1024 + k0 + ks + 8) = o1;
}

__global__ __launch_bounds__(256) void transpose_wp(const float* __restrict__ Wp,
                                                    unsigned short* __restrict__ WpT){
  __shared__ float tile[64][65];
  const int k0 = blockIdx.x * 64, c0 = blockIdx.y * 64;
  const int tid = threadIdx.x;
  {
    const int r = tid >> 2, cs = (tid & 3) << 4;
    #pragma unroll
    for (int q = 0; q < 4; ++q){
      f32x4 v = *(const f32x4*)(Wp + (size_t)(k0+r)*1024 + c0 + cs + q*4);
      tile[r][cs+q*4+0]=v.x; tile[r][cs+q*4+1]=v.y; tile[r][cs+q*4+2]=v.z; tile[r][cs+q*4+3]=v.w;
    }
  }
  __syncthreads();
  const int c = tid >> 2, ks = (tid & 3) << 4;
  bf16x8 o0, o1;
  #pragma unroll
  for (int x = 0; x < 8; ++x) o0[x] = (short)f2bf(tile[ks + x][c]);
  #pragma unroll
  for (int x = 0; x < 8; ++x) o1[x] = (short)f2bf(tile[ks + 8 + x][c]);
  *(bf16x8*)(WpT + (size_t)(c0 + c) * 1024 + k0 + ks)     = o0;
  *(bf16x8*)(WpT + (size_t)(c0 + c) * 1024 + k0 + ks + 8) = o1;
}

__global__ void build_bias(const float* __restrict__ bq, const float* __restrict__ br,
                           float* __restrict__ bias){
  const int c = blockIdx.x * 256 + threadIdx.x;
  if (c >= 3328) return;
  float v = 0.f;
  if (c < 1024) v = bq[c] * 0.125f;
  else if (c >= 3072 && c < 3232) v = br[c - 3072];
  bias[c] = v;
}

// Vt[h][d][t] <- Y[t][2048 + h*64 + d]
__global__ __launch_bounds__(256) void vt_transpose(const unsigned short* __restrict__ Y,
                                                    unsigned short* __restrict__ Vt){
  __shared__ unsigned short tile[64][72];
  const int h = blockIdx.y, t0 = blockIdx.x * 64;
  const int tid = threadIdx.x;
  {
    const int r = tid >> 2, cs = (tid & 3) << 4;
    const unsigned short* src = Y + (size_t)(t0 + r) * LDY2 + 2048 + h * 64 + cs;
    *(bf16x8*)&tile[r][cs]     = *(const bf16x8*)src;
    *(bf16x8*)&tile[r][cs + 8] = *(const bf16x8*)(src + 8);
  }
  __syncthreads();
  const int d = tid >> 2, ts = (tid & 3) << 4;
  bf16x8 o0, o1;
  #pragma unroll
  for (int x = 0; x < 8; ++x) o0[x] = (short)tile[ts + x][d];
  #pragma unroll
  for (int x = 0; x < 8; ++x) o1[x] = (short)tile[ts + 8 + x][d];
  *(bf16x8*)(Vt + (size_t)(h*64 + d) * 2048 + t0 + ts)     = o0;
  *(bf16x8*)(Vt + (size_t)(h*64 + d) * 2048 + t0 + ts + 8) = o1;
}

// BndT[t'][32]: t' = rel + 64, t' in [0,2176); cols n<10 = bnd[n][rel], else 0
__global__ __launch_bounds__(256) void build_bndt(const float* __restrict__ bnd,
                                                  unsigned short* __restrict__ BndT){
  const int t = blockIdx.x * 256 + threadIdx.x;
  if (t >= 2176) return;
  const int rel = t - 64;
  unsigned short* dst = BndT + (size_t)t * 32;
  bf16x8 v0 = {}, v1 = {}, z = {};
  if (rel >= 0 && rel < 2048){
    #pragma unroll
    for (int n = 0; n < 8; ++n) v0[n] = (short)f2bf(bnd[n * 2048 + rel]);
    v1[0] = (short)f2bf(bnd[8 * 2048 + rel]);
    v1[1] = (short)f2bf(bnd[9 * 2048 + rel]);
  }
  *(bf16x8*)dst        = v0;
  *(bf16x8*)(dst + 8)  = v1;
  *(bf16x8*)(dst + 16) = z;
  *(bf16x8*)(dst + 24) = z;
}

// ---------------- bf16 MFMA GEMM (m97 structure) ----------------

__global__ __launch_bounds__(256) void gemm_bf16(
    const unsigned short* __restrict__ A,
    const unsigned short* __restrict__ BT,
    const float* __restrict__ bias,
    void* __restrict__ C, int ldc, int out_f32)
{
  __shared__ unsigned short As[128 * 64];
  __shared__ unsigned short Bs[128 * 64];
  const int tid = threadIdx.x;
  const int w = tid >> 6, lane = tid & 63;
  const int lid = lane & 15, lgrp = lane >> 4;
  const int wm = w >> 1, wn = w & 1;
  const int row0 = blockIdx.y << 7, col0 = blockIdx.x << 7;
  const int sr = lane >> 3;
  const int sc = (lane & 7) ^ sr;

  f32x4 acc[4][4] = {};

  for (int k0 = 0; k0 < 1024; k0 += 64){
    #pragma unroll
    for (int it = 0; it < 4; ++it){
      const int r0w = (w << 5) + (it << 3);
      const int r = r0w + sr;
      __builtin_amdgcn_global_load_lds(GLB(A  + (size_t)(row0 + r) * 1024 + k0 + (sc << 3)),
                                       LDSP(&As[r0w << 6]), 16, 0, 0);
      __builtin_amdgcn_global_load_lds(GLB(BT + (size_t)(col0 + r) * 1024 + k0 + (sc << 3)),
                                       LDSP(&Bs[r0w << 6]), 16, 0, 0);
    }
    __syncthreads();

    bf16x8 af[4][2], bfr[4][2];
    #pragma unroll
    for (int m = 0; m < 4; ++m){
      const int ra = wm * 64 + m * 16 + lid;
      const int rb = wn * 64 + m * 16 + lid;
      #pragma unroll
      for (int kk = 0; kk < 2; ++kk){
        const int kc = kk * 4 + lgrp;
        af[m][kk]  = *(const bf16x8*)&As[(ra << 6) + ((kc ^ (lid & 7)) << 3)];
        bfr[m][kk] = *(const bf16x8*)&Bs[(rb << 6) + ((kc ^ (lid & 7)) << 3)];
      }
    }
    #pragma unroll
    for (int m = 0; m < 4; ++m)
      #pragma unroll
      for (int n = 0; n < 4; ++n){
        acc[m][n] = MFMA16(af[m][0], bfr[n][0], acc[m][n]);
        acc[m][n] = MFMA16(af[m][1], bfr[n][1], acc[m][n]);
      }
    __syncthreads();
  }

  #pragma unroll
  for (int m = 0; m < 4; ++m){
    #pragma unroll
    for (int n = 0; n < 4; ++n){
      const int col = col0 + wn * 64 + n * 16 + lid;
      const float bv = bias[col];
      #pragma unroll
      for (int i = 0; i < 4; ++i){
        const int row = row0 + wm * 64 + m * 16 + lgrp * 4 + i;
        const float v = acc[m][n][i] + bv;
        if (out_f32) ((float*)C)[(size_t)row * ldc + col] = v;
        else ((unsigned short*)C)[(size_t)row * ldc + col] = f2bf(v);
      }
    }
  }
}

// ---------------- fused flash attention -------------------------------------
// 512 blocks x 256 thr. Block = (h, pair p, q-half qh): processes rows
// [qbA*64 + qh*32, +32) over qbA's full kv range, then same rows of qbB=31-p.
// Duration = ceil((qbA+1)/2) + ceil((qbB+1)/2) = 17 lockstep iters, uniform.
// Waves: w = wq + 2*grp. grp = kv-parity group (tiles kb%2==grp), own K/V
// buffer; wq = q-wave (16 rows). Per-group online softmax; exact merge in LDS.
// El (bf16, [16][80]) unioned with Pl per wave: el reads precede P writes.

__global__ __launch_bounds__(256) void attn_mfma(
    const unsigned short* __restrict__ Y,
    const unsigned short* __restrict__ Vt,
    const unsigned short* __restrict__ BndT,
    unsigned short* __restrict__ AO)
{
  __shared__ unsigned short KV[4][4096];  // K(grp0), K(grp1), V(grp0), V(grp1)
  __shared__ unsigned short UN[4][1280];  // per-wave union: El bf16 [16][80] / Pl [16][64]

  const int id = blockIdx.x;
  const int h = id & 15;
  const int u = id >> 4;              // [0,32)
  const int p = u >> 1, qh = u & 1;
  const int tid = threadIdx.x;
  const int w = tid >> 6, lane = tid & 63;
  const int wq = w & 1, grp = w >> 1;
  const int lid = lane & 15, lgrp = lane >> 4;
  const int sr = lane >> 3;
  const int scc = (lane & 7) ^ sr;

  unsigned short* Ksg = &KV[grp][0];
  unsigned short* Vsg = &KV[2 + grp][0];
  unsigned short* un  = &UN[w][0];

  #pragma unroll
  for (int seg = 0; seg < 2; ++seg){
    const int qb = seg ? (31 - p) : p;
    const int q0b = qb * 64 + qh * 32;          // 32-row base for this block
    const int nt = qb + 1;
    const int L = (nt + 1) >> 1;

    // loop-invariant fragments for this segment's rows
    const int qrow = q0b + wq * 16 + lid;
    bf16x8 qf[2];
    #pragma unroll
    for (int kk = 0; kk < 2; ++kk)
      qf[kk] = *(const bf16x8*)(Y + (size_t)qrow * LDY2 + h*64 + ((kk*4 + lgrp) << 3));

    bf16x8 rf = {};
    {
      const unsigned* rp = (const unsigned*)(Y + (size_t)qrow * LDY2 + 3072 + h*10);
      if (lgrp == 0){
        #pragma unroll
        for (int x = 0; x < 4; ++x) ((unsigned*)&rf)[x] = rp[x];
      } else if (lgrp == 1){
        ((unsigned*)&rf)[0] = rp[4];
      }
    }

    float m_i = -INFINITY, l_i = 0.f;
    f32x4 o[4] = {};

    for (int it = 0; it < L; ++it){
      const int kb = 2 * it + grp;
      const bool active = (kb < nt);
      const int j0 = kb << 6;
      const int d0 = q0b - j0;

      if (active){
        // stage K [j][d] and V^T [d][j] for this group's tile (2 waves, 4 rounds)
        #pragma unroll
        for (int st = 0; st < 4; ++st){
          const int r0w = wq * 32 + st * 8;
          const int r = r0w + sr;
          __builtin_amdgcn_global_load_lds(GLB(Y  + (size_t)(j0 + r) * LDY2 + 1024 + h*64 + (scc << 3)),
                                           LDSP(&Ksg[r0w << 6]), 16, 0, 0);
          __builtin_amdgcn_global_load_lds(GLB(Vt + (size_t)(h*64 + r) * 2048 + j0 + (scc << 3)),
                                           LDSP(&Vsg[r0w << 6]), 16, 0, 0);
        }
      }
      __syncthreads();

      if (active){
        // band-table loads (latency overlaps S-MFMAs)
        bf16x8 bw[5];
        #pragma unroll
        for (int f = 0; f < 5; ++f){
          const int rowt = d0 + 1 + (wq + f) * 16 + lid;   // rel + 64
          bw[f] = *(const bf16x8*)(BndT + ((size_t)rowt << 5) + (lgrp << 3));
        }

        // S^T = K Q^T : s[n4][i] = S[q=lid][j = n4*16 + lgrp*4 + i]
        f32x4 s[4] = {};
        __builtin_amdgcn_s_setprio(1);
        #pragma unroll
        for (int kk = 0; kk < 2; ++kk){
          const int kc = kk * 4 + lgrp;
          #pragma unroll
          for (int n4 = 0; n4 < 4; ++n4){
            const bf16x8 kf = *(const bf16x8*)&Ksg[((n4*16 + lid) << 6) + ((kc ^ (lid & 7)) << 3)];
            s[n4] = MFMA16(kf, qf[kk], s[n4]);
          }
        }
        __builtin_amdgcn_s_setprio(0);

        // E window via MFMA -> bf16 el[q][c], c = f*16+lid, rel(c)=d0+wq*16+c-63
        #pragma unroll
        for (int f = 0; f < 5; ++f){
          f32x4 ef = {};
          ef = MFMA16(rf, bw[f], ef);
          #pragma unroll
          for (int i = 0; i < 4; ++i)
            un[(lgrp*4 + i) * 80 + f*16 + lid] = f2bf_rn(ef[i]);
        }

        // bias gather + causal mask
        const bool diag = (kb == qb);
        const int ql = qh*32 + wq*16 + lid;      // local-64 q index
        #pragma unroll
        for (int n4 = 0; n4 < 4; ++n4){
          #pragma unroll
          for (int i = 0; i < 4; ++i){
            const int jl = n4*16 + lgrp*4 + i;
            float v = s[n4][i] + bf2f(un[lid * 80 + (lid - jl + 63)]);
            if (diag && jl > ql) v = -1e9f;
            s[n4][i] = v;
          }
        }

        // in-register online softmax (per-lane row q=lid), defer-max THR=8
        float rm = s[0][0];
        #pragma unroll
        for (int n4 = 0; n4 < 4; ++n4)
          #pragma unroll
          for (int i = 0; i < 4; ++i) rm = fmaxf(rm, s[n4][i]);
        rm = fmaxf(rm, __shfl_xor(rm, 16));
        rm = fmaxf(rm, __shfl_xor(rm, 32));

        if (__all(rm - m_i <= 8.f)){
          float rs = 0.f;
          #pragma unroll
          for (int n4 = 0; n4 < 4; ++n4)
            #pragma unroll
            for (int i = 0; i < 4; ++i){
              const float pv = __expf(s[n4][i] - m_i);
              s[n4][i] = pv;
              rs += pv;
            }
          rs += __shfl_xor(rs, 16);
          rs += __shfl_xor(rs, 32);
          l_i += rs;
        } else {
          const float mn = fmaxf(m_i, rm);
          const float sc_ = __expf(m_i - mn);
          m_i = mn;
          float rs = 0.f;
          #pragma unroll
          for (int n4 = 0; n4 < 4; ++n4)
            #pragma unroll
            for (int i = 0; i < 4; ++i){
              const float pv = __expf(s[n4][i] - mn);
              s[n4][i] = pv;
              rs += pv;
            }
          rs += __shfl_xor(rs, 16);
          rs += __shfl_xor(rs, 32);
          l_i = l_i * sc_ + rs;
          #pragma unroll
          for (int n4 = 0; n4 < 4; ++n4)
            #pragma unroll
            for (int i = 0; i < 4; ++i) o[n4][i] *= sc_;
        }

        // P -> wave-local LDS (union area; el reads above are complete)
        #pragma unroll
        for (int n4 = 0; n4 < 4; ++n4){
          const unsigned a = ((unsigned)f2bf_rn(s[n4][0])) | (((unsigned)f2bf_rn(s[n4][1])) << 16);
          const unsigned b = ((unsigned)f2bf_rn(s[n4][2])) | (((unsigned)f2bf_rn(s[n4][3])) << 16);
          const int chunk = (n4*2 + (lgrp >> 1)) ^ (lid & 7);
          const int base = (lid << 6) + (chunk << 3) + ((lgrp & 1) << 2);
          *(unsigned*)&un[base]     = a;
          *(unsigned*)&un[base + 2] = b;
        }

        // O^T += V^T P^T
        __builtin_amdgcn_s_setprio(1);
        #pragma unroll
        for (int kk = 0; kk < 2; ++kk){
          const int kc = kk * 4 + lgrp;
          const bf16x8 pb = *(const bf16x8*)&un[(lid << 6) + ((kc ^ (lid & 7)) << 3)];
          #pragma unroll
          for (int n4 = 0; n4 < 4; ++n4){
            const bf16x8 vf = *(const bf16x8*)&Vsg[((n4*16 + lid) << 6) + ((kc ^ (lid & 7)) << 3)];
            o[n4] = MFMA16(vf, pb, o[n4]);
          }
        }
        __builtin_amdgcn_s_setprio(0);
      }
      __syncthreads();
    }

    // ---- merge the two kv-groups (exact) ----
    float* oScr  = (float*)&KV[0][0];            // [2 wq][16 lid][68]
    float* mlScr = oScr + 2 * 16 * 68;           // [2 wq][16 lid][2]
    if (grp == 1){
      const int base = (wq * 16 + lid) * 68;
      #pragma unroll
      for (int n4 = 0; n4 < 4; ++n4)
        *(f32x4*)&oScr[base + n4*16 + lgrp*4] = o[n4];
      if (lgrp == 0){
        mlScr[(wq * 16 + lid) * 2 + 0] = m_i;
        mlScr[(wq * 16 + lid) * 2 + 1] = l_i;
      }
    }
    __syncthreads();
    if (grp == 0){
      const int base = (wq * 16 + lid) * 68;
      const float m1 = mlScr[(wq * 16 + lid) * 2 + 0];
      const float l1 = mlScr[(wq * 16 + lid) * 2 + 1];
      const float M  = fmaxf(m_i, m1);
      const float a  = __expf(m_i - M);
      const float b  = __expf(m1 - M);
      const float inv = 1.f / (l_i * a + l1 * b);
      unsigned short* dst = AO + (size_t)qrow * 1024 + h * 64;
      #pragma unroll
      for (int n4 = 0; n4 < 4; ++n4){
        const f32x4 o1 = *(const f32x4*)&oScr[base + n4*16 + lgrp*4];
        const float v0 = (o[n4][0]*a + o1[0]*b) * inv;
        const float v1 = (o[n4][1]*a + o1[1]*b) * inv;
        const float v2 = (o[n4][2]*a + o1[2]*b) * inv;
        const float v3 = (o[n4][3]*a + o1[3]*b) * inv;
        unsigned r0 = ((unsigned)f2bf_rn(v0)) | (((unsigned)f2bf_rn(v1)) << 16);
        unsigned r1 = ((unsigned)f2bf_rn(v2)) | (((unsigned)f2bf_rn(v3)) << 16);
        unsigned long long pk = ((unsigned long long)r1 << 32) | r0;
        *(unsigned long long*)(dst + n4*16 + lgrp*4) = pk;
      }
    }
    __syncthreads();   // scratch (KV) free before next segment's staging
  }
}

// ---------------- launch ----------------

extern "C" void kernel_launch(void* const* d_in, const int* in_sizes, int n_in,
                              void* d_out, int out_size, void* d_ws, size_t ws_size,
                              hipStream_t stream) {
  const float* X   = (const float*)d_in[0];
  const float* Wq  = (const float*)d_in[1];
  const float* bq  = (const float*)d_in[2];
  const float* Wk  = (const float*)d_in[3];
  const float* Wv  = (const float*)d_in[4];
  const float* Wp  = (const float*)d_in[5];
  const float* bp  = (const float*)d_in[6];
  const float* Wr  = (const float*)d_in[7];
  const float* br  = (const float*)d_in[8];
  const float* bnd = (const float*)d_in[9];
  float* out = (float*)d_out;

  unsigned short* Xb  = (unsigned short*)d_ws;            // 2048*1024 (reused as AO)
  unsigned short* WbT = Xb  + (size_t)2048 * 1024;        // 3328*1024 (BndT alias after gemm)
  unsigned short* Yb  = WbT + (size_t)3328 * 1024;        // 2048*3328
  unsigned short* Vt  = Yb  + (size_t)2048 * 3328;        // 1024*2048
  unsigned short* WpT = Vt  + (size_t)1024 * 2048;        // 1024*1024
  float* bias = (float*)(WpT + (size_t)1024 * 1024);      // 3328
  unsigned short* AO   = Xb;    // Xb dead after projection GEMM
  unsigned short* BndT = WbT;   // WbT dead after projection GEMM

  convert_x   <<<1024,         256, 0, stream>>>(X, Xb);
  pack_wbt    <<<dim3(16, 52), 256, 0, stream>>>(Wq, Wk, Wv, Wr, WbT);
  transpose_wp<<<dim3(16, 16), 256, 0, stream>>>(Wp, WpT);
  build_bias  <<<13,           256, 0, stream>>>(bq, br, bias);

  gemm_bf16   <<<dim3(26, 16), 256, 0, stream>>>(Xb, WbT, bias, Yb, 3328, 0);
  vt_transpose<<<dim3(32, 16), 256, 0, stream>>>(Yb, Vt);
  build_bndt  <<<9,            256, 0, stream>>>(bnd, BndT);
  attn_mfma   <<<512,          256, 0, stream>>>(Yb, Vt, BndT, AO);
  gemm_bf16   <<<dim3(8, 16),  256, 0, stream>>>(AO, WpT, bp, out, 1024, 1);
}

// Round 10
// 111.745 us; speedup vs baseline: 1.2976x; 1.1396x over previous
//
#include <hip/hip_runtime.h>
#include <hip/hip_bf16.h>
#include <math.h>

// Problem: B=1, T=2048, E=1024, H=16, DH=64, NB=10, ML=2048
// Pipeline (all bf16 MFMA):
//   prep_mega: Xb = bf16(X); WbT = [Wq*0.125|Wk|Wv|Wr]^T; WpT = Wp^T; bias
//   gemm1: Y[2048][3328] = Xb @ Wb + bias   (Q|K|V|R)
//   post_mega: Vt[h][d][t] = V^T per head; BndT table (in WbT pad rows)
//   attn: flash-attention, uniform-duration blocks + 2 kv-parity groups
//   gemm2 (64x128 tiles, 256 blocks): out = AO @ Wp + bp (f32)

typedef __attribute__((ext_vector_type(8))) short bf16x8;
typedef __attribute__((ext_vector_type(4))) float f32x4;

#define MFMA16(a,b,c) __builtin_amdgcn_mfma_f32_16x16x32_bf16((a),(b),(c),0,0,0)
#define GLB(p)  ((const __attribute__((address_space(1))) void*)(p))
#define LDSP(p) ((__attribute__((address_space(3))) void*)(p))
#define LDY2 3328

__device__ __forceinline__ unsigned short f2bf(float x){
  unsigned u = __float_as_uint(x);
  u = (u + 0x7FFFu + ((u >> 16) & 1u)) >> 16;
  return (unsigned short)u;
}
__device__ __forceinline__ unsigned short f2bf_rn(float x){
  __hip_bfloat16 b = __float2bfloat16(x);
  return *reinterpret_cast<unsigned short*>(&b);
}
__device__ __forceinline__ float bf2f(unsigned short b){
  return __uint_as_float(((unsigned)b) << 16);
}

// ---------------- fused prep kernel (convert_x | pack_wbt | transpose_wp | bias)

__global__ __launch_bounds__(256) void prep_mega(
    const float* __restrict__ X,
    const float* __restrict__ Wq, const float* __restrict__ Wk,
    const float* __restrict__ Wv, const float* __restrict__ Wr,
    const float* __restrict__ Wp,
    const float* __restrict__ bq, const float* __restrict__ br,
    unsigned short* __restrict__ Xb, unsigned short* __restrict__ WbT,
    unsigned short* __restrict__ WpT, float* __restrict__ bias)
{
  __shared__ float tile[64][65];
  const int b = blockIdx.x;
  const int tid = threadIdx.x;

  if (b < 1024){
    // convert X -> bf16
    const int i = (b * 256 + tid) * 8;
    f32x4 a = *(const f32x4*)(X + i);
    f32x4 v2 = *(const f32x4*)(X + i + 4);
    bf16x8 v;
    v[0]=(short)f2bf(a.x); v[1]=(short)f2bf(a.y); v[2]=(short)f2bf(a.z); v[3]=(short)f2bf(a.w);
    v[4]=(short)f2bf(v2.x); v[5]=(short)f2bf(v2.y); v[6]=(short)f2bf(v2.z); v[7]=(short)f2bf(v2.w);
    *(bf16x8*)(Xb + i) = v;
    return;
  }
  if (b < 1024 + 832){
    // pack WbT[c][k]; Q cols prescaled 0.125
    const int idx = b - 1024;
    const int k0 = (idx & 15) * 64, c0 = (idx >> 4) * 64;
    {
      const int r = tid >> 2, cs = (tid & 3) << 4;
      #pragma unroll
      for (int q = 0; q < 4; ++q){
        const int c = c0 + cs + q * 4;
        f32x4 v;
        if (c < 1024){
          v = *(const f32x4*)(Wq + (size_t)(k0+r)*1024 + c);
          v.x *= 0.125f; v.y *= 0.125f; v.z *= 0.125f; v.w *= 0.125f;
        }
        else if (c < 2048) v = *(const f32x4*)(Wk + (size_t)(k0+r)*1024 + (c-1024));
        else if (c < 3072) v = *(const f32x4*)(Wv + (size_t)(k0+r)*1024 + (c-2048));
        else if (c < 3232) v = *(const f32x4*)(Wr + (size_t)(k0+r)*160  + (c-3072));
        else               v = (f32x4){0.f,0.f,0.f,0.f};
        tile[r][cs+q*4+0]=v.x; tile[r][cs+q*4+1]=v.y; tile[r][cs+q*4+2]=v.z; tile[r][cs+q*4+3]=v.w;
      }
    }
    __syncthreads();
    const int c = tid >> 2, ks = (tid & 3) << 4;
    bf16x8 o0, o1;
    #pragma unroll
    for (int x = 0; x < 8; ++x) o0[x] = (short)f2bf(tile[ks + x][c]);
    #pragma unroll
    for (int x = 0; x < 8; ++x) o1[x] = (short)f2bf(tile[ks + 8 + x][c]);
    *(bf16x8*)(WbT + (size_t)(c0 + c) * 1024 + k0 + ks)     = o0;
    *(bf16x8*)(WbT + (size_t)(c0 + c) * 1024 + k0 + ks + 8) = o1;
    return;
  }
  if (b < 1024 + 832 + 256){
    // transpose Wp
    const int idx = b - 1856;
    const int k0 = (idx & 15) * 64, c0 = (idx >> 4) * 64;
    {
      const int r = tid >> 2, cs = (tid & 3) << 4;
      #pragma unroll
      for (int q = 0; q < 4; ++q){
        f32x4 v = *(const f32x4*)(Wp + (size_t)(k0+r)*1024 + c0 + cs + q*4);
        tile[r][cs+q*4+0]=v.x; tile[r][cs+q*4+1]=v.y; tile[r][cs+q*4+2]=v.z; tile[r][cs+q*4+3]=v.w;
      }
    }
    __syncthreads();
    const int c = tid >> 2, ks = (tid & 3) << 4;
    bf16x8 o0, o1;
    #pragma unroll
    for (int x = 0; x < 8; ++x) o0[x] = (short)f2bf(tile[ks + x][c]);
    #pragma unroll
    for (int x = 0; x < 8; ++x) o1[x] = (short)f2bf(tile[ks + 8 + x][c]);
    *(bf16x8*)(WpT + (size_t)(c0 + c) * 1024 + k0 + ks)     = o0;
    *(bf16x8*)(WpT + (size_t)(c0 + c) * 1024 + k0 + ks + 8) = o1;
    return;
  }
  // bias
  const int c = (b - 2112) * 256 + tid;
  if (c < 3328){
    float v = 0.f;
    if (c < 1024) v = bq[c] * 0.125f;
    else if (c >= 3072 && c < 3232) v = br[c - 3072];
    bias[c] = v;
  }
}

// ---------------- fused post kernel (vt_transpose | build_bndt) --------------

__global__ __launch_bounds__(256) void post_mega(
    const unsigned short* __restrict__ Y, const float* __restrict__ bnd,
    unsigned short* __restrict__ Vt, unsigned short* __restrict__ BndT)
{
  __shared__ unsigned short tile[64][72];
  const int b = blockIdx.x;
  const int tid = threadIdx.x;

  if (b < 512){
    const int h = b >> 5, t0 = (b & 31) * 64;
    {
      const int r = tid >> 2, cs = (tid & 3) << 4;
      const unsigned short* src = Y + (size_t)(t0 + r) * LDY2 + 2048 + h * 64 + cs;
      *(bf16x8*)&tile[r][cs]     = *(const bf16x8*)src;
      *(bf16x8*)&tile[r][cs + 8] = *(const bf16x8*)(src + 8);
    }
    __syncthreads();
    const int d = tid >> 2, ts = (tid & 3) << 4;
    bf16x8 o0, o1;
    #pragma unroll
    for (int x = 0; x < 8; ++x) o0[x] = (short)tile[ts + x][d];
    #pragma unroll
    for (int x = 0; x < 8; ++x) o1[x] = (short)tile[ts + 8 + x][d];
    *(bf16x8*)(Vt + (size_t)(h*64 + d) * 2048 + t0 + ts)     = o0;
    *(bf16x8*)(Vt + (size_t)(h*64 + d) * 2048 + t0 + ts + 8) = o1;
    return;
  }
  // BndT[t'][32]: t' = rel + 64, rel in [-64, 2112)
  const int t = (b - 512) * 256 + tid;
  if (t >= 2176) return;
  const int rel = t - 64;
  unsigned short* dst = BndT + (size_t)t * 32;
  bf16x8 v0 = {}, v1 = {}, z = {};
  if (rel >= 0 && rel < 2048){
    #pragma unroll
    for (int n = 0; n < 8; ++n) v0[n] = (short)f2bf(bnd[n * 2048 + rel]);
    v1[0] = (short)f2bf(bnd[8 * 2048 + rel]);
    v1[1] = (short)f2bf(bnd[9 * 2048 + rel]);
  }
  *(bf16x8*)dst        = v0;
  *(bf16x8*)(dst + 8)  = v1;
  *(bf16x8*)(dst + 16) = z;
  *(bf16x8*)(dst + 24) = z;
}

// ---------------- bf16 MFMA GEMM, 128x128 tile (projection) -----------------

__global__ __launch_bounds__(256) void gemm_bf16(
    const unsigned short* __restrict__ A,
    const unsigned short* __restrict__ BT,
    const float* __restrict__ bias,
    unsigned short* __restrict__ C, int ldc)
{
  __shared__ unsigned short As[128 * 64];
  __shared__ unsigned short Bs[128 * 64];
  const int tid = threadIdx.x;
  const int w = tid >> 6, lane = tid & 63;
  const int lid = lane & 15, lgrp = lane >> 4;
  const int wm = w >> 1, wn = w & 1;
  const int row0 = blockIdx.y << 7, col0 = blockIdx.x << 7;
  const int sr = lane >> 3;
  const int sc = (lane & 7) ^ sr;

  f32x4 acc[4][4] = {};

  for (int k0 = 0; k0 < 1024; k0 += 64){
    #pragma unroll
    for (int it = 0; it < 4; ++it){
      const int r0w = (w << 5) + (it << 3);
      const int r = r0w + sr;
      __builtin_amdgcn_global_load_lds(GLB(A  + (size_t)(row0 + r) * 1024 + k0 + (sc << 3)),
                                       LDSP(&As[r0w << 6]), 16, 0, 0);
      __builtin_amdgcn_global_load_lds(GLB(BT + (size_t)(col0 + r) * 1024 + k0 + (sc << 3)),
                                       LDSP(&Bs[r0w << 6]), 16, 0, 0);
    }
    __syncthreads();

    bf16x8 af[4][2], bfr[4][2];
    #pragma unroll
    for (int m = 0; m < 4; ++m){
      const int ra = wm * 64 + m * 16 + lid;
      const int rb = wn * 64 + m * 16 + lid;
      #pragma unroll
      for (int kk = 0; kk < 2; ++kk){
        const int kc = kk * 4 + lgrp;
        af[m][kk]  = *(const bf16x8*)&As[(ra << 6) + ((kc ^ (lid & 7)) << 3)];
        bfr[m][kk] = *(const bf16x8*)&Bs[(rb << 6) + ((kc ^ (lid & 7)) << 3)];
      }
    }
    #pragma unroll
    for (int m = 0; m < 4; ++m)
      #pragma unroll
      for (int n = 0; n < 4; ++n){
        acc[m][n] = MFMA16(af[m][0], bfr[n][0], acc[m][n]);
        acc[m][n] = MFMA16(af[m][1], bfr[n][1], acc[m][n]);
      }
    __syncthreads();
  }

  #pragma unroll
  for (int m = 0; m < 4; ++m){
    #pragma unroll
    for (int n = 0; n < 4; ++n){
      const int col = col0 + wn * 64 + n * 16 + lid;
      const float bv = bias[col];
      #pragma unroll
      for (int i = 0; i < 4; ++i){
        const int row = row0 + wm * 64 + m * 16 + lgrp * 4 + i;
        C[(size_t)row * ldc + col] = f2bf(acc[m][n][i] + bv);
      }
    }
  }
}

// ---------------- bf16 MFMA GEMM, 64x128 tile, f32 out (out-projection) -----

__global__ __launch_bounds__(256) void gemm_bf16_out(
    const unsigned short* __restrict__ A,
    const unsigned short* __restrict__ BT,
    const float* __restrict__ bias,
    float* __restrict__ C)
{
  __shared__ unsigned short As[64 * 64];
  __shared__ unsigned short Bs[128 * 64];
  const int tid = threadIdx.x;
  const int w = tid >> 6, lane = tid & 63;
  const int lid = lane & 15, lgrp = lane >> 4;
  const int wm = w >> 1, wn = w & 1;
  const int row0 = blockIdx.y << 6, col0 = blockIdx.x << 7;
  const int sr = lane >> 3;
  const int sc = (lane & 7) ^ sr;

  f32x4 acc[2][4] = {};

  for (int k0 = 0; k0 < 1024; k0 += 64){
    #pragma unroll
    for (int it = 0; it < 2; ++it){
      const int r0w = (w << 4) + (it << 3);
      const int r = r0w + sr;
      __builtin_amdgcn_global_load_lds(GLB(A + (size_t)(row0 + r) * 1024 + k0 + (sc << 3)),
                                       LDSP(&As[r0w << 6]), 16, 0, 0);
    }
    #pragma unroll
    for (int it = 0; it < 4; ++it){
      const int r0w = (w << 5) + (it << 3);
      const int r = r0w + sr;
      __builtin_amdgcn_global_load_lds(GLB(BT + (size_t)(col0 + r) * 1024 + k0 + (sc << 3)),
                                       LDSP(&Bs[r0w << 6]), 16, 0, 0);
    }
    __syncthreads();

    bf16x8 af[2][2], bfr[4][2];
    #pragma unroll
    for (int m = 0; m < 2; ++m){
      const int ra = wm * 32 + m * 16 + lid;
      #pragma unroll
      for (int kk = 0; kk < 2; ++kk){
        const int kc = kk * 4 + lgrp;
        af[m][kk] = *(const bf16x8*)&As[(ra << 6) + ((kc ^ (lid & 7)) << 3)];
      }
    }
    #pragma unroll
    for (int n = 0; n < 4; ++n){
      const int rb = wn * 64 + n * 16 + lid;
      #pragma unroll
      for (int kk = 0; kk < 2; ++kk){
        const int kc = kk * 4 + lgrp;
        bfr[n][kk] = *(const bf16x8*)&Bs[(rb << 6) + ((kc ^ (lid & 7)) << 3)];
      }
    }
    #pragma unroll
    for (int m = 0; m < 2; ++m)
      #pragma unroll
      for (int n = 0; n < 4; ++n){
        acc[m][n] = MFMA16(af[m][0], bfr[n][0], acc[m][n]);
        acc[m][n] = MFMA16(af[m][1], bfr[n][1], acc[m][n]);
      }
    __syncthreads();
  }

  #pragma unroll
  for (int m = 0; m < 2; ++m){
    #pragma unroll
    for (int n = 0; n < 4; ++n){
      const int col = col0 + wn * 64 + n * 16 + lid;
      const float bv = bias[col];
      #pragma unroll
      for (int i = 0; i < 4; ++i){
        const int row = row0 + wm * 32 + m * 16 + lgrp * 4 + i;
        C[(size_t)row * 1024 + col] = acc[m][n][i] + bv;
      }
    }
  }
}

// ---------------- fused flash attention (unchanged from r9) -----------------

__global__ __launch_bounds__(256) void attn_mfma(
    const unsigned short* __restrict__ Y,
    const unsigned short* __restrict__ Vt,
    const unsigned short* __restrict__ BndT,
    unsigned short* __restrict__ AO)
{
  __shared__ unsigned short KV[4][4096];  // K(grp0), K(grp1), V(grp0), V(grp1)
  __shared__ unsigned short UN[4][1280];  // per-wave union: El bf16 [16][80] / Pl [16][64]

  const int id = blockIdx.x;
  const int h = id & 15;
  const int u = id >> 4;
  const int p = u >> 1, qh = u & 1;
  const int tid = threadIdx.x;
  const int w = tid >> 6, lane = tid & 63;
  const int wq = w & 1, grp = w >> 1;
  const int lid = lane & 15, lgrp = lane >> 4;
  const int sr = lane >> 3;
  const int scc = (lane & 7) ^ sr;

  unsigned short* Ksg = &KV[grp][0];
  unsigned short* Vsg = &KV[2 + grp][0];
  unsigned short* un  = &UN[w][0];

  #pragma unroll
  for (int seg = 0; seg < 2; ++seg){
    const int qb = seg ? (31 - p) : p;
    const int q0b = qb * 64 + qh * 32;
    const int nt = qb + 1;
    const int L = (nt + 1) >> 1;

    const int qrow = q0b + wq * 16 + lid;
    bf16x8 qf[2];
    #pragma unroll
    for (int kk = 0; kk < 2; ++kk)
      qf[kk] = *(const bf16x8*)(Y + (size_t)qrow * LDY2 + h*64 + ((kk*4 + lgrp) << 3));

    bf16x8 rf = {};
    {
      const unsigned* rp = (const unsigned*)(Y + (size_t)qrow * LDY2 + 3072 + h*10);
      if (lgrp == 0){
        #pragma unroll
        for (int x = 0; x < 4; ++x) ((unsigned*)&rf)[x] = rp[x];
      } else if (lgrp == 1){
        ((unsigned*)&rf)[0] = rp[4];
      }
    }

    float m_i = -INFINITY, l_i = 0.f;
    f32x4 o[4] = {};

    for (int it = 0; it < L; ++it){
      const int kb = 2 * it + grp;
      const bool active = (kb < nt);
      const int j0 = kb << 6;
      const int d0 = q0b - j0;

      if (active){
        #pragma unroll
        for (int st = 0; st < 4; ++st){
          const int r0w = wq * 32 + st * 8;
          const int r = r0w + sr;
          __builtin_amdgcn_global_load_lds(GLB(Y  + (size_t)(j0 + r) * LDY2 + 1024 + h*64 + (scc << 3)),
                                           LDSP(&Ksg[r0w << 6]), 16, 0, 0);
          __builtin_amdgcn_global_load_lds(GLB(Vt + (size_t)(h*64 + r) * 2048 + j0 + (scc << 3)),
                                           LDSP(&Vsg[r0w << 6]), 16, 0, 0);
        }
      }
      __syncthreads();

      if (active){
        bf16x8 bw[5];
        #pragma unroll
        for (int f = 0; f < 5; ++f){
          const int rowt = d0 + 1 + (wq + f) * 16 + lid;
          bw[f] = *(const bf16x8*)(BndT + ((size_t)rowt << 5) + (lgrp << 3));
        }

        f32x4 s[4] = {};
        __builtin_amdgcn_s_setprio(1);
        #pragma unroll
        for (int kk = 0; kk < 2; ++kk){
          const int kc = kk * 4 + lgrp;
          #pragma unroll
          for (int n4 = 0; n4 < 4; ++n4){
            const bf16x8 kf = *(const bf16x8*)&Ksg[((n4*16 + lid) << 6) + ((kc ^ (lid & 7)) << 3)];
            s[n4] = MFMA16(kf, qf[kk], s[n4]);
          }
        }
        __builtin_amdgcn_s_setprio(0);

        #pragma unroll
        for (int f = 0; f < 5; ++f){
          f32x4 ef = {};
          ef = MFMA16(rf, bw[f], ef);
          #pragma unroll
          for (int i = 0; i < 4; ++i)
            un[(lgrp*4 + i) * 80 + f*16 + lid] = f2bf_rn(ef[i]);
        }

        const bool diag = (kb == qb);
        const int ql = qh*32 + wq*16 + lid;
        #pragma unroll
        for (int n4 = 0; n4 < 4; ++n4){
          #pragma unroll
          for (int i = 0; i < 4; ++i){
            const int jl = n4*16 + lgrp*4 + i;
            float v = s[n4][i] + bf2f(un[lid * 80 + (lid - jl + 63)]);
            if (diag && jl > ql) v = -1e9f;
            s[n4][i] = v;
          }
        }

        float rm = s[0][0];
        #pragma unroll
        for (int n4 = 0; n4 < 4; ++n4)
          #pragma unroll
          for (int i = 0; i < 4; ++i) rm = fmaxf(rm, s[n4][i]);
        rm = fmaxf(rm, __shfl_xor(rm, 16));
        rm = fmaxf(rm, __shfl_xor(rm, 32));

        if (__all(rm - m_i <= 8.f)){
          float rs = 0.f;
          #pragma unroll
          for (int n4 = 0; n4 < 4; ++n4)
            #pragma unroll
            for (int i = 0; i < 4; ++i){
              const float pv = __expf(s[n4][i] - m_i);
              s[n4][i] = pv;
              rs += pv;
            }
          rs += __shfl_xor(rs, 16);
          rs += __shfl_xor(rs, 32);
          l_i += rs;
        } else {
          const float mn = fmaxf(m_i, rm);
          const float sc_ = __expf(m_i - mn);
          m_i = mn;
          float rs = 0.f;
          #pragma unroll
          for (int n4 = 0; n4 < 4; ++n4)
            #pragma unroll
            for (int i = 0; i < 4; ++i){
              const float pv = __expf(s[n4][i] - mn);
              s[n4][i] = pv;
              rs += pv;
            }
          rs += __shfl_xor(rs, 16);
          rs += __shfl_xor(rs, 32);
          l_i = l_i * sc_ + rs;
          #pragma unroll
          for (int n4 = 0; n4 < 4; ++n4)
            #pragma unroll
            for (int i = 0; i < 4; ++i) o[n4][i] *= sc_;
        }

        #pragma unroll
        for (int n4 = 0; n4 < 4; ++n4){
          const unsigned a = ((unsigned)f2bf_rn(s[n4][0])) | (((unsigned)f2bf_rn(s[n4][1])) << 16);
          const unsigned b = ((unsigned)f2bf_rn(s[n4][2])) | (((unsigned)f2bf_rn(s[n4][3])) << 16);
          const int chunk = (n4*2 + (lgrp >> 1)) ^ (lid & 7);
          const int base = (lid << 6) + (chunk << 3) + ((lgrp & 1) << 2);
          *(unsigned*)&un[base]     = a;
          *(unsigned*)&un[base + 2] = b;
        }

        __builtin_amdgcn_s_setprio(1);
        #pragma unroll
        for (int kk = 0; kk < 2; ++kk){
          const int kc = kk * 4 + lgrp;
          const bf16x8 pb = *(const bf16x8*)&un[(lid << 6) + ((kc ^ (lid & 7)) << 3)];
          #pragma unroll
          for (int n4 = 0; n4 < 4; ++n4){
            const bf16x8 vf = *(const bf16x8*)&Vsg[((n4*16 + lid) << 6) + ((kc ^ (lid & 7)) << 3)];
            o[n4] = MFMA16(vf, pb, o[n4]);
          }
        }
        __builtin_amdgcn_s_setprio(0);
      }
      __syncthreads();
    }

    // merge the two kv-groups (exact)
    float* oScr  = (float*)&KV[0][0];
    float* mlScr = oScr + 2 * 16 * 68;
    if (grp == 1){
      const int base = (wq * 16 + lid) * 68;
      #pragma unroll
      for (int n4 = 0; n4 < 4; ++n4)
        *(f32x4*)&oScr[base + n4*16 + lgrp*4] = o[n4];
      if (lgrp == 0){
        mlScr[(wq * 16 + lid) * 2 + 0] = m_i;
        mlScr[(wq * 16 + lid) * 2 + 1] = l_i;
      }
    }
    __syncthreads();
    if (grp == 0){
      const int base = (wq * 16 + lid) * 68;
      const float m1 = mlScr[(wq * 16 + lid) * 2 + 0];
      const float l1 = mlScr[(wq * 16 + lid) * 2 + 1];
      const float M  = fmaxf(m_i, m1);
      const float a  = __expf(m_i - M);
      const float b  = __expf(m1 - M);
      const float inv = 1.f / (l_i * a + l1 * b);
      unsigned short* dst = AO + (size_t)qrow * 1024 + h * 64;
      #pragma unroll
      for (int n4 = 0; n4 < 4; ++n4){
        const f32x4 o1 = *(const f32x4*)&oScr[base + n4*16 + lgrp*4];
        const float v0 = (o[n4][0]*a + o1[0]*b) * inv;
        const float v1 = (o[n4][1]*a + o1[1]*b) * inv;
        const float v2 = (o[n4][2]*a + o1[2]*b) * inv;
        const float v3 = (o[n4][3]*a + o1[3]*b) * inv;
        unsigned r0 = ((unsigned)f2bf_rn(v0)) | (((unsigned)f2bf_rn(v1)) << 16);
        unsigned r1 = ((unsigned)f2bf_rn(v2)) | (((unsigned)f2bf_rn(v3)) << 16);
        unsigned long long pk = ((unsigned long long)r1 << 32) | r0;
        *(unsigned long long*)(dst + n4*16 + lgrp*4) = pk;
      }
    }
    __syncthreads();
  }
}

// ---------------- launch ----------------

extern "C" void kernel_launch(void* const* d_in, const int* in_sizes, int n_in,
                              void* d_out, int out_size, void* d_ws, size_t ws_size,
                              hipStream_t stream) {
  const float* X   = (const float*)d_in[0];
  const float* Wq  = (const float*)d_in[1];
  const float* bq  = (const float*)d_in[2];
  const float* Wk  = (const float*)d_in[3];
  const float* Wv  = (const float*)d_in[4];
  const float* Wp  = (const float*)d_in[5];
  const float* bp  = (const float*)d_in[6];
  const float* Wr  = (const float*)d_in[7];
  const float* br  = (const float*)d_in[8];
  const float* bnd = (const float*)d_in[9];
  float* out = (float*)d_out;

  unsigned short* Xb  = (unsigned short*)d_ws;            // 2048*1024 (reused as AO)
  unsigned short* WbT = Xb  + (size_t)2048 * 1024;        // 3328*1024
  unsigned short* Yb  = WbT + (size_t)3328 * 1024;        // 2048*3328
  unsigned short* Vt  = Yb  + (size_t)2048 * 3328;        // 1024*2048
  unsigned short* WpT = Vt  + (size_t)1024 * 2048;        // 1024*1024
  float* bias = (float*)(WpT + (size_t)1024 * 1024);      // 3328
  unsigned short* AO   = Xb;                    // Xb dead after gemm1
  unsigned short* BndT = WbT + (size_t)3232 * 1024;  // WbT pad rows (dead after gemm1):
                                                     // 96*1024*2B = 192KB >= 2176*32*2B

  prep_mega    <<<2125,         256, 0, stream>>>(X, Wq, Wk, Wv, Wr, Wp, bq, br,
                                                  Xb, WbT, WpT, bias);
  gemm_bf16    <<<dim3(26, 16), 256, 0, stream>>>(Xb, WbT, bias, Yb, 3328);
  post_mega    <<<521,          256, 0, stream>>>(Yb, bnd, Vt, BndT);
  attn_mfma    <<<512,          256, 0, stream>>>(Yb, Vt, BndT, AO);
  gemm_bf16_out<<<dim3(8, 32),  256, 0, stream>>>(AO, WpT, bp, out);
}